// Round 9
// baseline (15.525 us; speedup 1.0000x reference)
//
#include <hip/hip_runtime.h>

// TBSyntaxParser v9: v8 single-kernel structure + issue-order surgery.
// Per-wave VMEM issue order: gather idx -> slab0 W1 -> gather buffer float4
// -> (pack slab0, write) -> slab1 W1 loads -> B0 ds_reads -> gather pack +
// Afrag writes -> slab1 pack/write -> B1 ds_reads -> barrier -> MFMA.
// All long-latency loads are in flight before any consumer waits.
// B=4096, L=128, D=60, X=360(k, pad 384), HID=200(n), OUT=3.
// d_out = [out (B*3) | legal (B*3)] f32.

#define Bq    4096
#define Lq    128
#define Dq    60
#define HIDq  200
#define ONUM  3
#define KTN   12        // k-tiles (384/32)
#define MB    16        // states per block (MFMA M)
#define NTHR  512       // 8 waves
#define SLABW 196       // words per n-column (192 k-pairs + 4 pad; %32=4 bank spread)

typedef short bf16x8 __attribute__((ext_vector_type(8)));
typedef float f32x4  __attribute__((ext_vector_type(4)));

__device__ __forceinline__ unsigned int rhu(float f) {
    union { float f; unsigned int u; } x; x.f = f;
    return x.u + 0x8000u;                      // round-half-up into bf16 slot
}
// pack two rounded floats -> (bf16(hi)<<16) | bf16(lo) in one v_perm_b32
__device__ __forceinline__ int pack2(float lo, float hi) {
    return (int)__builtin_amdgcn_perm(rhu(hi), rhu(lo), 0x07060302u);
}

__global__ __launch_bounds__(NTHR, 1) void parser_fused(
    const float* __restrict__ buffer,
    const float* __restrict__ W1,
    const float* __restrict__ b1,
    const float* __restrict__ W2,
    const float* __restrict__ b2,
    const int*   __restrict__ buffer_index,
    const int*   __restrict__ stack_indexes,
    const int*   __restrict__ stack_len,
    float*       __restrict__ out)
{
    __shared__ unsigned short Afrag[KTN * 64 * 8];     // 12 KiB, A-fragment packed
    __shared__ unsigned int   wbuf[8][16 * SLABW];     // 100.4 KiB wave-private W1 slabs
    __shared__ float          psum[8][MB][ONUM];       // 1.5 KiB wave partials

    const int t  = threadIdx.x;
    const int w  = t >> 6;
    const int l  = t & 63;
    const int s0 = blockIdx.x * MB;
    const bool hasB1 = (w < 5);

    // ================= PHASE A: gather index loads (FIRST in VMEM FIFO) ====
    int g_s[3], g_row[3], g_k0[3];
    #pragma unroll
    for (int m = 0; m < 3; ++m) {
        int i = t + m * 512;
        bool ok = (m < 2) || (t < 416);              // 1440 jobs total
        if (ok) {
            int s = i / 90, r = i % 90, seg = r / 15, f = r % 15;
            g_s[m]  = s;
            g_k0[m] = seg * 60 + f * 4;
            g_row[m] = (seg < 3) ? (buffer_index[s0 + s] + seg)
                                 : stack_indexes[(s0 + s) * 3 + (seg - 3)];
        } else { g_s[m] = 0; g_row[m] = 0; g_k0[m] = 0; }
    }

    // ================= PHASE B: slab0 W1 loads (n-tile w, always valid) ====
    float4 s0a[12], s0b[12];
    #pragma unroll
    for (int it = 0; it < 12; ++it) {
        int j = it * 64 + l;
        if (it < 11 || l < 16) {                     // j < 720
            int k2 = j >> 2, nq = j & 3;
            int nb = w * 16 + nq * 4;                // <= 124 < 200: no guard
            const float* p = W1 + (size_t)(2 * k2) * HIDq + nb;
            s0a[it] = *(const float4*)p;
            s0b[it] = *(const float4*)(p + HIDq);
        }
    }

    // epilogue constants (small, independent)
    const int  n0   = w * 16 + (l & 15);             // <= 127
    const int  n1   = (8 + w) * 16 + (l & 15);
    const bool n1ok = n1 < HIDq;
    float bb0 = b1[n0];
    float w20 = W2[n0 * ONUM + 0], w21 = W2[n0 * ONUM + 1], w22 = W2[n0 * ONUM + 2];
    float bb1 = 0.f, w23 = 0.f, w24 = 0.f, w25 = 0.f;
    if (hasB1 && n1ok) {
        bb1 = b1[n1];
        w23 = W2[n1 * ONUM + 0]; w24 = W2[n1 * ONUM + 1]; w25 = W2[n1 * ONUM + 2];
    }

    // ================= PHASE C: gather buffer float4 loads (L3 latency) ====
    float4 gv[3];
    #pragma unroll
    for (int m = 0; m < 3; ++m) {
        bool ok = (m < 2) || (t < 416);
        if (ok) {
            int off = g_k0[m] % 60;                  // offset within the 60-float row
            gv[m] = *(const float4*)(buffer +
                     ((size_t)(s0 + g_s[m]) * Lq + g_row[m]) * Dq + off);
        }
    }

    // zero wbuf k-pad words k2 in [180,192) for this wave's 16 columns
    #pragma unroll
    for (int z = 0; z < 3; ++z) {
        int idx = z * 64 + l;
        wbuf[w][(idx / 12) * SLABW + 180 + (idx % 12)] = 0u;
    }

    // ================= PHASE D: slab0 pack + ds_write =====================
    #pragma unroll
    for (int it = 0; it < 12; ++it) {
        int j = it * 64 + l;
        if (it < 11 || l < 16) {
            int k2 = j >> 2, nq = j & 3;
            wbuf[w][(nq * 4 + 0) * SLABW + k2] = (unsigned)pack2(s0a[it].x, s0b[it].x);
            wbuf[w][(nq * 4 + 1) * SLABW + k2] = (unsigned)pack2(s0a[it].y, s0b[it].y);
            wbuf[w][(nq * 4 + 2) * SLABW + k2] = (unsigned)pack2(s0a[it].z, s0b[it].z);
            wbuf[w][(nq * 4 + 3) * SLABW + k2] = (unsigned)pack2(s0a[it].w, s0b[it].w);
        }
    }

    // ================= PHASE E: slab1 W1 loads (issued before any B reads) =
    float4 s1a[12], s1b[12];
    if (hasB1) {
        #pragma unroll
        for (int it = 0; it < 12; ++it) {
            int j = it * 64 + l;
            if (it < 11 || l < 16) {
                int k2 = j >> 2, nq = j & 3;
                int nb = 128 + w * 16 + nq * 4;      // may reach 204 for w==4
                if (nb < HIDq) {
                    const float* p = W1 + (size_t)(2 * k2) * HIDq + nb;
                    s1a[it] = *(const float4*)p;
                    s1b[it] = *(const float4*)(p + HIDq);
                } else {
                    s1a[it] = (float4){0.f, 0.f, 0.f, 0.f};
                    s1b[it] = (float4){0.f, 0.f, 0.f, 0.f};
                }
            }
        }
    }

    // ================= PHASE H0: B0 fragment ds_reads (slab0 complete) =====
    bf16x8 B0[KTN], B1[KTN];
    #pragma unroll
    for (int kt = 0; kt < KTN; ++kt)
        B0[kt] = *((const bf16x8*)&wbuf[w][(l & 15) * SLABW + kt * 16 + ((l >> 4) << 2)]);

    // ================= PHASE F: gather pack + Afrag writes + legal mask ====
    #pragma unroll
    for (int m = 0; m < 3; ++m) {
        bool ok = (m < 2) || (t < 416);
        if (ok) {
            int kt   = g_k0[m] >> 5;
            int lane = g_s[m] + (((g_k0[m] & 31) >> 3) << 4);
            uint2 pk;
            pk.x = (unsigned)pack2(gv[m].x, gv[m].y);
            pk.y = (unsigned)pack2(gv[m].z, gv[m].w);
            *((uint2*)&Afrag[(size_t)(kt * 64 + lane) * 8 + (g_k0[m] & 7)]) = pk;
        }
    }
    // zero Afrag k-pad of kt=11 (lanes 16..63 hold k in [360,384))
    if (t < 48) {
        f32x4 z = {0.f, 0.f, 0.f, 0.f};
        *((f32x4*)&Afrag[(size_t)(11 * 64 + 16 + t) * 8]) = z;
    }
    // legal mask (independent of MLP)
    if (t < MB * ONUM) {
        int s = t / ONUM, o = t % ONUM;
        int bi = buffer_index[s0 + s];
        int sl = stack_len[s0 + s];
        float lg;
        if (o == 0)      lg = (bi + 3 >= Lq) ? 0.f : 1.f;
        else if (o == 1) lg = (sl <= 3)      ? 0.f : 1.f;
        else             lg = (sl <= 4)      ? 0.f : 1.f;
        out[(size_t)Bq * ONUM + (size_t)(s0 + s) * ONUM + o] = lg;
    }

    // ================= PHASE G: slab1 pack + ds_write, then B1 reads =======
    if (hasB1) {
        #pragma unroll
        for (int it = 0; it < 12; ++it) {
            int j = it * 64 + l;
            if (it < 11 || l < 16) {
                int k2 = j >> 2, nq = j & 3;
                wbuf[w][(nq * 4 + 0) * SLABW + k2] = (unsigned)pack2(s1a[it].x, s1b[it].x);
                wbuf[w][(nq * 4 + 1) * SLABW + k2] = (unsigned)pack2(s1a[it].y, s1b[it].y);
                wbuf[w][(nq * 4 + 2) * SLABW + k2] = (unsigned)pack2(s1a[it].z, s1b[it].z);
                wbuf[w][(nq * 4 + 3) * SLABW + k2] = (unsigned)pack2(s1a[it].w, s1b[it].w);
            }
        }
        #pragma unroll
        for (int kt = 0; kt < KTN; ++kt)
            B1[kt] = *((const bf16x8*)&wbuf[w][(l & 15) * SLABW + kt * 16 + ((l >> 4) << 2)]);
    }

    __syncthreads();

    // ================= layer 1 MFMA: A from LDS, B in registers ============
    f32x4 acc0 = {}, acc1 = {};
    #pragma unroll
    for (int kt = 0; kt < KTN; ++kt) {
        bf16x8 a = *((const bf16x8*)&Afrag[(size_t)(kt * 64 + l) * 8]);
        acc0 = __builtin_amdgcn_mfma_f32_16x16x32_bf16(a, B0[kt], acc0, 0, 0, 0);
        if (hasB1)
            acc1 = __builtin_amdgcn_mfma_f32_16x16x32_bf16(a, B1[kt], acc1, 0, 0, 0);
    }

    // ================= fused epilogue: bias + ReLU + layer-2 ==============
    // lane holds hid_pre[s = (l>>4)*4 + r][j = nt*16 + (l&15)] in acc[r]
    float p[ONUM][4];
    #pragma unroll
    for (int o = 0; o < ONUM; ++o)
        #pragma unroll
        for (int r = 0; r < 4; ++r) p[o][r] = 0.f;

    #pragma unroll
    for (int r = 0; r < 4; ++r) {
        float h = acc0[r] + bb0; h = h > 0.f ? h : 0.f;
        p[0][r] = fmaf(h, w20, p[0][r]);
        p[1][r] = fmaf(h, w21, p[1][r]);
        p[2][r] = fmaf(h, w22, p[2][r]);
    }
    if (hasB1) {
        #pragma unroll
        for (int r = 0; r < 4; ++r) {
            float h = acc1[r] + bb1; h = h > 0.f ? h : 0.f;   // consts 0 if n1>=200
            p[0][r] = fmaf(h, w23, p[0][r]);
            p[1][r] = fmaf(h, w24, p[1][r]);
            p[2][r] = fmaf(h, w25, p[2][r]);
        }
    }

    // butterfly-reduce over the 16-lane j-group
    #pragma unroll
    for (int d = 1; d < 16; d <<= 1) {
        #pragma unroll
        for (int o = 0; o < ONUM; ++o)
            #pragma unroll
            for (int r = 0; r < 4; ++r)
                p[o][r] += __shfl_xor(p[o][r], d, 64);
    }
    if ((l & 15) == 0) {
        #pragma unroll
        for (int r = 0; r < 4; ++r) {
            int s = ((l >> 4) << 2) + r;
            #pragma unroll
            for (int o = 0; o < ONUM; ++o) psum[w][s][o] = p[o][r];
        }
    }
    __syncthreads();

    // ================= combine 8 wave-partials + bias ======================
    if (t < MB * ONUM) {
        int s = t / ONUM, o = t % ONUM;
        float v = b2[o];
        #pragma unroll
        for (int w8 = 0; w8 < 8; ++w8) v += psum[w8][s][o];
        out[(size_t)(s0 + s) * ONUM + o] = v;
    }
}

extern "C" void kernel_launch(void* const* d_in, const int* in_sizes, int n_in,
                              void* d_out, int out_size, void* d_ws, size_t ws_size,
                              hipStream_t stream) {
    const float* buffer        = (const float*)d_in[0];
    const float* W1            = (const float*)d_in[1];
    const float* b1            = (const float*)d_in[2];
    const float* W2            = (const float*)d_in[3];
    const float* b2            = (const float*)d_in[4];
    const int*   buffer_index  = (const int*)d_in[5];
    const int*   stack_indexes = (const int*)d_in[6];
    const int*   stack_len     = (const int*)d_in[7];
    float*       out           = (float*)d_out;

    parser_fused<<<Bq / MB, NTHR, 0, stream>>>(
        buffer, W1, b1, W2, b2, buffer_index, stack_indexes, stack_len, out);
}

// Round 10
// 14.571 us; speedup vs baseline: 1.0654x; 1.0654x over previous
//
#include <hip/hip_runtime.h>

// TBSyntaxParser v10: v8 single-kernel + issue-order surgery with BOUNDED
// register staging (one W1 slab's arrays live at a time; peak ~185 VGPR).
// Per-wave VMEM order: gather idx -> slab0 W1 (reg-staged, deep pipeline) ->
// gather buffer float4 -> pack0/write0 -> slab1 W1 -> epi consts -> B0 ds_read
// -> gather pack/Afrag/legal -> pack1/write1 -> B1 ds_read -> barrier -> MFMA.
// B=4096, L=128, D=60, X=360(k, pad 384), HID=200(n), OUT=3.
// d_out = [out (B*3) | legal (B*3)] f32.

#define Bq    4096
#define Lq    128
#define Dq    60
#define HIDq  200
#define ONUM  3
#define KTN   12        // k-tiles (384/32)
#define MB    16        // states per block (MFMA M)
#define NTHR  512       // 8 waves
#define SLABW 196       // words per n-column (192 k-pairs + 4 pad)

typedef short bf16x8 __attribute__((ext_vector_type(8)));
typedef float f32x4  __attribute__((ext_vector_type(4)));

__device__ __forceinline__ unsigned int rhu(float f) {
    union { float f; unsigned int u; } x; x.f = f;
    return x.u + 0x8000u;                      // round-half-up into bf16 slot
}
// pack two rounded floats -> (bf16(hi)<<16) | bf16(lo) in one v_perm_b32
__device__ __forceinline__ int pack2(float lo, float hi) {
    return (int)__builtin_amdgcn_perm(rhu(hi), rhu(lo), 0x07060302u);
}

__global__ __launch_bounds__(NTHR, 1) void parser_fused(
    const float* __restrict__ buffer,
    const float* __restrict__ W1,
    const float* __restrict__ b1,
    const float* __restrict__ W2,
    const float* __restrict__ b2,
    const int*   __restrict__ buffer_index,
    const int*   __restrict__ stack_indexes,
    const int*   __restrict__ stack_len,
    float*       __restrict__ out)
{
    __shared__ unsigned short Afrag[KTN * 64 * 8];     // 12 KiB
    __shared__ unsigned int   wbuf[8][16 * SLABW];     // 100.4 KiB wave-private
    __shared__ float          psum[8][MB][ONUM];       // 1.5 KiB

    const int t  = threadIdx.x;
    const int w  = t >> 6;
    const int l  = t & 63;
    const int s0 = blockIdx.x * MB;
    const bool hasB1 = (w < 5);

    // ---- P1: gather index loads (oldest in VMEM FIFO) ----
    int g_s[3], g_k0[3], g_seg[3], g_ri[3];
    bool g_ok[3];
    #pragma unroll
    for (int m = 0; m < 3; ++m) {
        int i = t + m * 512;
        g_ok[m] = (m < 2) || (t < 416);              // 1440 jobs
        if (g_ok[m]) {
            int s = i / 90, r = i % 90, seg = r / 15, f = r % 15;
            g_s[m] = s; g_seg[m] = seg; g_k0[m] = seg * 60 + f * 4;
            g_ri[m] = (seg < 3) ? buffer_index[s0 + s]
                                : stack_indexes[(s0 + s) * 3 + (seg - 3)];
        } else { g_s[m] = 0; g_seg[m] = 0; g_k0[m] = 0; g_ri[m] = 0; }
    }

    // ---- P2: slab0 W1 loads, register-staged (24 loads in flight) ----
    float4 sa[12], sb[12];
    #pragma unroll
    for (int it = 0; it < 12; ++it) {
        int j = it * 64 + l;
        if (it < 11 || l < 16) {                     // j < 720
            int k2 = j >> 2, nq = j & 3;
            int nb = w * 16 + nq * 4;                // <= 124, no guard
            const float* p = W1 + (size_t)(2 * k2) * HIDq + nb;
            sa[it] = *(const float4*)p;
            sb[it] = *(const float4*)(p + HIDq);
        }
    }

    // ---- P3: gather buffer float4 loads (dep only on idx; issues early) ----
    float4 gv[3];
    #pragma unroll
    for (int m = 0; m < 3; ++m) {
        if (g_ok[m]) {
            int row = (g_seg[m] < 3) ? (g_ri[m] + g_seg[m]) : g_ri[m];
            int off = g_k0[m] % 60;
            gv[m] = *(const float4*)(buffer +
                     ((size_t)(s0 + g_s[m]) * Lq + row) * Dq + off);
        } else {
            gv[m] = (float4){0.f, 0.f, 0.f, 0.f};
        }
    }

    // zero wbuf k-pad words k2 in [180,192) for this wave's 16 columns
    #pragma unroll
    for (int z = 0; z < 3; ++z) {
        int idx = z * 64 + l;
        wbuf[w][(idx / 12) * SLABW + 180 + (idx % 12)] = 0u;
    }

    // ---- P4: pack slab0 + ds_write (waits slab0 loads; gv stays in flight) ----
    #pragma unroll
    for (int it = 0; it < 12; ++it) {
        int j = it * 64 + l;
        if (it < 11 || l < 16) {
            int k2 = j >> 2, nq = j & 3;
            wbuf[w][(nq * 4 + 0) * SLABW + k2] = (unsigned)pack2(sa[it].x, sb[it].x);
            wbuf[w][(nq * 4 + 1) * SLABW + k2] = (unsigned)pack2(sa[it].y, sb[it].y);
            wbuf[w][(nq * 4 + 2) * SLABW + k2] = (unsigned)pack2(sa[it].z, sb[it].z);
            wbuf[w][(nq * 4 + 3) * SLABW + k2] = (unsigned)pack2(sa[it].w, sb[it].w);
        }
    }

    // ---- P5: slab1 W1 loads, register-staged (sa/sb now dead; regs reused) ----
    float4 ta[12], tb[12];
    if (hasB1) {
        #pragma unroll
        for (int it = 0; it < 12; ++it) {
            int j = it * 64 + l;
            if (it < 11 || l < 16) {
                int k2 = j >> 2, nq = j & 3;
                int nb = 128 + w * 16 + nq * 4;      // up to 204 for w==4
                if (nb < HIDq) {
                    const float* p = W1 + (size_t)(2 * k2) * HIDq + nb;
                    ta[it] = *(const float4*)p;
                    tb[it] = *(const float4*)(p + HIDq);
                } else {
                    ta[it] = (float4){0.f, 0.f, 0.f, 0.f};
                    tb[it] = (float4){0.f, 0.f, 0.f, 0.f};
                }
            }
        }
    }

    // ---- epilogue constants (small; latency hidden until after barrier) ----
    const int  n0   = w * 16 + (l & 15);
    const int  n1   = (8 + w) * 16 + (l & 15);
    const bool n1ok = n1 < HIDq;
    float bb0 = b1[n0];
    float w20 = W2[n0 * ONUM + 0], w21 = W2[n0 * ONUM + 1], w22 = W2[n0 * ONUM + 2];
    float bb1 = 0.f, w23 = 0.f, w24 = 0.f, w25 = 0.f;
    if (hasB1 && n1ok) {
        bb1 = b1[n1];
        w23 = W2[n1 * ONUM + 0]; w24 = W2[n1 * ONUM + 1]; w25 = W2[n1 * ONUM + 2];
    }

    // ---- P6: B0 fragment ds_reads (slab0 written; same-wave lgkm order) ----
    bf16x8 B0[KTN], B1[KTN];
    #pragma unroll
    for (int kt = 0; kt < KTN; ++kt)
        B0[kt] = *((const bf16x8*)&wbuf[w][(l & 15) * SLABW + kt * 16 + ((l >> 4) << 2)]);

    // ---- P7: gather pack + Afrag writes + legal mask (gv arrived by now) ----
    #pragma unroll
    for (int m = 0; m < 3; ++m) {
        if (g_ok[m]) {
            int kt   = g_k0[m] >> 5;
            int lane = g_s[m] + (((g_k0[m] & 31) >> 3) << 4);
            uint2 pk;
            pk.x = (unsigned)pack2(gv[m].x, gv[m].y);
            pk.y = (unsigned)pack2(gv[m].z, gv[m].w);
            *((uint2*)&Afrag[(size_t)(kt * 64 + lane) * 8 + (g_k0[m] & 7)]) = pk;
        }
    }
    if (t < 48) {                                    // zero Afrag kt=11 pad
        f32x4 z = {0.f, 0.f, 0.f, 0.f};
        *((f32x4*)&Afrag[(size_t)(11 * 64 + 16 + t) * 8]) = z;
    }
    if (t < MB * ONUM) {                             // legal mask
        int s = t / ONUM, o = t % ONUM;
        int bi = buffer_index[s0 + s];
        int sl = stack_len[s0 + s];
        float lg;
        if (o == 0)      lg = (bi + 3 >= Lq) ? 0.f : 1.f;
        else if (o == 1) lg = (sl <= 3)      ? 0.f : 1.f;
        else             lg = (sl <= 4)      ? 0.f : 1.f;
        out[(size_t)Bq * ONUM + (size_t)(s0 + s) * ONUM + o] = lg;
    }

    // ---- P8: pack slab1 + ds_write, then B1 reads (WAR safe: in-order DS) ----
    if (hasB1) {
        #pragma unroll
        for (int it = 0; it < 12; ++it) {
            int j = it * 64 + l;
            if (it < 11 || l < 16) {
                int k2 = j >> 2, nq = j & 3;
                wbuf[w][(nq * 4 + 0) * SLABW + k2] = (unsigned)pack2(ta[it].x, tb[it].x);
                wbuf[w][(nq * 4 + 1) * SLABW + k2] = (unsigned)pack2(ta[it].y, tb[it].y);
                wbuf[w][(nq * 4 + 2) * SLABW + k2] = (unsigned)pack2(ta[it].z, tb[it].z);
                wbuf[w][(nq * 4 + 3) * SLABW + k2] = (unsigned)pack2(ta[it].w, tb[it].w);
            }
        }
        #pragma unroll
        for (int kt = 0; kt < KTN; ++kt)
            B1[kt] = *((const bf16x8*)&wbuf[w][(l & 15) * SLABW + kt * 16 + ((l >> 4) << 2)]);
    }

    __syncthreads();

    // ---- layer 1 MFMA: A from LDS, B in registers ----
    f32x4 acc0 = {}, acc1 = {};
    #pragma unroll
    for (int kt = 0; kt < KTN; ++kt) {
        bf16x8 a = *((const bf16x8*)&Afrag[(size_t)(kt * 64 + l) * 8]);
        acc0 = __builtin_amdgcn_mfma_f32_16x16x32_bf16(a, B0[kt], acc0, 0, 0, 0);
        if (hasB1)
            acc1 = __builtin_amdgcn_mfma_f32_16x16x32_bf16(a, B1[kt], acc1, 0, 0, 0);
    }

    // ---- fused epilogue: bias + ReLU + layer-2 partials in-register ----
    float p[ONUM][4];
    #pragma unroll
    for (int o = 0; o < ONUM; ++o)
        #pragma unroll
        for (int r = 0; r < 4; ++r) p[o][r] = 0.f;

    #pragma unroll
    for (int r = 0; r < 4; ++r) {
        float h = acc0[r] + bb0; h = h > 0.f ? h : 0.f;
        p[0][r] = fmaf(h, w20, p[0][r]);
        p[1][r] = fmaf(h, w21, p[1][r]);
        p[2][r] = fmaf(h, w22, p[2][r]);
    }
    if (hasB1) {
        #pragma unroll
        for (int r = 0; r < 4; ++r) {
            float h = acc1[r] + bb1; h = h > 0.f ? h : 0.f;
            p[0][r] = fmaf(h, w23, p[0][r]);
            p[1][r] = fmaf(h, w24, p[1][r]);
            p[2][r] = fmaf(h, w25, p[2][r]);
        }
    }

    #pragma unroll
    for (int d = 1; d < 16; d <<= 1) {
        #pragma unroll
        for (int o = 0; o < ONUM; ++o)
            #pragma unroll
            for (int r = 0; r < 4; ++r)
                p[o][r] += __shfl_xor(p[o][r], d, 64);
    }
    if ((l & 15) == 0) {
        #pragma unroll
        for (int r = 0; r < 4; ++r) {
            int s = ((l >> 4) << 2) + r;
            #pragma unroll
            for (int o = 0; o < ONUM; ++o) psum[w][s][o] = p[o][r];
        }
    }
    __syncthreads();

    if (t < MB * ONUM) {
        int s = t / ONUM, o = t % ONUM;
        float v = b2[o];
        #pragma unroll
        for (int w8 = 0; w8 < 8; ++w8) v += psum[w8][s][o];
        out[(size_t)(s0 + s) * ONUM + o] = v;
    }
}

extern "C" void kernel_launch(void* const* d_in, const int* in_sizes, int n_in,
                              void* d_out, int out_size, void* d_ws, size_t ws_size,
                              hipStream_t stream) {
    const float* buffer        = (const float*)d_in[0];
    const float* W1            = (const float*)d_in[1];
    const float* b1            = (const float*)d_in[2];
    const float* W2            = (const float*)d_in[3];
    const float* b2            = (const float*)d_in[4];
    const int*   buffer_index  = (const int*)d_in[5];
    const int*   stack_indexes = (const int*)d_in[6];
    const int*   stack_len     = (const int*)d_in[7];
    float*       out           = (float*)d_out;

    parser_fused<<<Bq / MB, NTHR, 0, stream>>>(
        buffer, W1, b1, W2, b2, buffer_index, stack_indexes, stack_len, out);
}